// Round 2
// baseline (577.630 us; speedup 1.0000x reference)
//
#include <hip/hip_runtime.h>
#include <cstdint>
#include <cstddef>

#define F_IN 165
#define HC1 256   // heads*out_ch of layer 1
#define NEG_SLOPE 0.2f

static __device__ __forceinline__ float lrelu(float z) {
    return z > 0.f ? z : NEG_SLOPE * z;
}

// -------------------- GEMM1: h1[N,256] = x[N,165] @ W1[165,256] --------------------
__global__ __launch_bounds__(256) void k_gemm1(const float* __restrict__ x,
                                               const float* __restrict__ W,
                                               float* __restrict__ h, int nrows)
{
    __shared__ float xs[64][33];   // +1 pad
    __shared__ float ws[32][64];
    const int t  = threadIdx.x;
    const int rb = blockIdx.x, cb = blockIdx.y;
    const int row0 = rb * 64;
    const int tr = t >> 4, tc = t & 15;
    float acc[4][4] = {};
    for (int kb = 0; kb < F_IN; kb += 32) {
        const int kw = min(32, F_IN - kb);
        for (int i = t; i < 64 * 32; i += 256) {
            int r = i >> 5, k = i & 31;
            int gr = row0 + r;
            float v = 0.f;
            if (gr < nrows && k < kw) v = x[(size_t)gr * F_IN + kb + k];
            xs[r][k] = v;
        }
        for (int i = t; i < 32 * 64; i += 256) {
            int k = i >> 6, c = i & 63;
            float v = 0.f;
            if (k < kw) v = W[(size_t)(kb + k) * HC1 + cb * 64 + c];
            ws[k][c] = v;
        }
        __syncthreads();
        for (int k = 0; k < kw; ++k) {
            float a[4], b[4];
            #pragma unroll
            for (int i = 0; i < 4; ++i) a[i] = xs[tr * 4 + i][k];
            #pragma unroll
            for (int j = 0; j < 4; ++j) b[j] = ws[k][tc * 4 + j];
            #pragma unroll
            for (int i = 0; i < 4; ++i)
                #pragma unroll
                for (int j = 0; j < 4; ++j)
                    acc[i][j] += a[i] * b[j];
        }
        __syncthreads();
    }
    #pragma unroll
    for (int i = 0; i < 4; ++i) {
        int gr = row0 + tr * 4 + i;
        if (gr < nrows) {
            float4 v = make_float4(acc[i][0], acc[i][1], acc[i][2], acc[i][3]);
            *reinterpret_cast<float4*>(h + (size_t)gr * HC1 + cb * 64 + tc * 4) = v;
        }
    }
}

// -------------------- attention scalars layer 1: a_src/a_dst [N,4] --------------------
__global__ void k_att1(const float* __restrict__ h, const float* __restrict__ att_src,
                       const float* __restrict__ att_dst, float* __restrict__ asrc,
                       float* __restrict__ adst, int N)
{
    int idx = blockIdx.x * blockDim.x + threadIdx.x;   // n*4+head
    if (idx >= N * 4) return;
    int n = idx >> 2, head = idx & 3;
    const float4* hv = reinterpret_cast<const float4*>(h + (size_t)n * HC1 + head * 64);
    const float4* s4 = reinterpret_cast<const float4*>(att_src + head * 64);
    const float4* d4 = reinterpret_cast<const float4*>(att_dst + head * 64);
    float ss = 0.f, dd = 0.f;
    #pragma unroll
    for (int k = 0; k < 16; ++k) {
        float4 v = hv[k], a = s4[k], b = d4[k];
        ss += v.x * a.x + v.y * a.y + v.z * a.z + v.w * a.w;
        dd += v.x * b.x + v.y * b.y + v.z * b.z + v.w * b.w;
    }
    asrc[idx] = ss;
    adst[idx] = dd;
}

// -------------------- CSR build --------------------
__global__ void k_deg_init(int* __restrict__ deg, int N) {
    int i = blockIdx.x * blockDim.x + threadIdx.x;
    if (i < N) deg[i] = 1;   // self loop
}

__global__ void k_count(const int* __restrict__ dst, int* __restrict__ deg, int E) {
    int e = blockIdx.x * blockDim.x + threadIdx.x;
    if (e < E) atomicAdd(&deg[dst[e]], 1);
}

// phase 1: per-1024-item block local inclusive scan -> off[i+1], block sums
__global__ __launch_bounds__(256) void k_scanA(const int* __restrict__ deg,
                                               int* __restrict__ off,
                                               int* __restrict__ bsums, int n)
{
    __shared__ int s[256];
    const int b = blockIdx.x, t = threadIdx.x;
    const int base = b * 1024 + t * 4;
    int v[4];
    int sum = 0;
    #pragma unroll
    for (int j = 0; j < 4; ++j) {
        v[j] = (base + j < n) ? deg[base + j] : 0;
        sum += v[j];
    }
    s[t] = sum;
    __syncthreads();
    for (int d = 1; d < 256; d <<= 1) {
        int xv = (t >= d) ? s[t - d] : 0;
        __syncthreads();
        s[t] += xv;
        __syncthreads();
    }
    int run = s[t] - sum;   // exclusive over threads
    #pragma unroll
    for (int j = 0; j < 4; ++j) {
        run += v[j];
        if (base + j < n) off[base + j + 1] = run;
    }
    if (t == 255) bsums[b] = s[255];
    if (b == 0 && t == 0) off[0] = 0;
}

// phase 2: exclusive scan of block sums (single block, B<=128)
__global__ __launch_bounds__(128) void k_scanB(int* __restrict__ bsums, int B) {
    __shared__ int s[128];
    const int t = threadIdx.x;
    int v = (t < B) ? bsums[t] : 0;
    s[t] = v;
    __syncthreads();
    for (int d = 1; d < 128; d <<= 1) {
        int xv = (t >= d) ? s[t - d] : 0;
        __syncthreads();
        s[t] += xv;
        __syncthreads();
    }
    if (t < B) bsums[t] = s[t] - v;
}

// phase 3: add scanned block sums
__global__ void k_scanC(int* __restrict__ off, const int* __restrict__ bsums, int n) {
    int i = blockIdx.x * blockDim.x + threadIdx.x;
    if (i < n) off[i + 1] += bsums[i >> 10];
}

__global__ void k_copy_cursor(const int* __restrict__ off, int* __restrict__ cur, int n) {
    int i = blockIdx.x * blockDim.x + threadIdx.x;
    if (i < n) cur[i] = off[i];
}

__global__ void k_scatter(const int* __restrict__ src, const int* __restrict__ dst,
                          int* __restrict__ cur, int* __restrict__ srcs, int E, int N)
{
    int i = blockIdx.x * blockDim.x + threadIdx.x;
    if (i >= E + N) return;
    int s, d;
    if (i < E) { s = src[i]; d = dst[i]; }
    else       { s = i - E; d = i - E; }   // self loop
    int p = atomicAdd(&cur[d], 1);
    srcs[p] = s;
}

// -------------------- layer-1 aggregation + fused layer-2 projection --------------------
// one block (256 thr) per dst node; thread t owns channel t (head = t>>6)
__global__ __launch_bounds__(256) void k_agg1(const float* __restrict__ h1,
        const float* __restrict__ asrc1, const float* __restrict__ adst1,
        const int* __restrict__ off, const int* __restrict__ srcs,
        const float* __restrict__ b1, const float* __restrict__ W2,
        const float* __restrict__ as2, const float* __restrict__ ad2,
        float* __restrict__ h2, float* __restrict__ asrc2, float* __restrict__ adst2)
{
    const int n = blockIdx.x;
    const int t = threadIdx.x;
    const int head = t >> 6;
    __shared__ float w2s[512];
    w2s[t]       = W2[t];
    w2s[t + 256] = W2[t + 256];
    __syncthreads();

    const float adh = adst1[n * 4 + head];
    const int p0 = off[n], p1 = off[n + 1];
    float m = -INFINITY, ssum = 0.f, acc = 0.f;
    for (int p = p0; p < p1; ++p) {
        const int s = srcs[p];
        const float z = asrc1[s * 4 + head] + adh;
        const float l = lrelu(z);
        const float hv = h1[(size_t)s * HC1 + t];
        if (l > m) {
            const float sc = __expf(m - l);
            ssum *= sc; acc *= sc; m = l;
        }
        const float w = __expf(l - m);
        ssum += w;
        acc += w * hv;
    }
    float o = acc / ssum + b1[t];
    o = fmaxf(o, 0.f);                     // inter-layer ReLU

    // h2[n, 0:2] = o-row (256) @ W2 (256x2)
    float q0 = o * w2s[2 * t + 0];
    float q1 = o * w2s[2 * t + 1];
    #pragma unroll
    for (int d = 32; d > 0; d >>= 1) {
        q0 += __shfl_down(q0, d, 64);
        q1 += __shfl_down(q1, d, 64);
    }
    __shared__ float r0[4], r1[4];
    const int lane = t & 63, wv = t >> 6;
    if (lane == 0) { r0[wv] = q0; r1[wv] = q1; }
    __syncthreads();
    if (t == 0) {
        float h20 = r0[0] + r0[1] + r0[2] + r0[3];
        float h21 = r1[0] + r1[1] + r1[2] + r1[3];
        h2[n * 2 + 0] = h20;
        h2[n * 2 + 1] = h21;
        asrc2[n] = h20 * as2[0] + h21 * as2[1];
        adst2[n] = h20 * ad2[0] + h21 * ad2[1];
    }
}

// -------------------- layer-2 aggregation + log_softmax --------------------
__global__ void k_l2(const float* __restrict__ h2, const float* __restrict__ asrc2,
                     const float* __restrict__ adst2, const int* __restrict__ off,
                     const int* __restrict__ srcs, const float* __restrict__ b2,
                     float* __restrict__ out, int N)
{
    int n = blockIdx.x * blockDim.x + threadIdx.x;
    if (n >= N) return;
    const float adn = adst2[n];
    float m = -INFINITY, ssum = 0.f, a0 = 0.f, a1 = 0.f;
    const int p1 = off[n + 1];
    for (int p = off[n]; p < p1; ++p) {
        int s = srcs[p];
        float l = lrelu(asrc2[s] + adn);
        if (l > m) {
            float sc = __expf(m - l);
            ssum *= sc; a0 *= sc; a1 *= sc; m = l;
        }
        float w = __expf(l - m);
        ssum += w;
        a0 += w * h2[s * 2 + 0];
        a1 += w * h2[s * 2 + 1];
    }
    float o0 = a0 / ssum + b2[0];
    float o1 = a1 / ssum + b2[1];
    float mm = fmaxf(o0, o1);
    float lse = mm + __logf(__expf(o0 - mm) + __expf(o1 - mm));
    out[n * 2 + 0] = o0 - lse;
    out[n * 2 + 1] = o1 - lse;
}

extern "C" void kernel_launch(void* const* d_in, const int* in_sizes, int n_in,
                              void* d_out, int out_size, void* d_ws, size_t ws_size,
                              hipStream_t stream)
{
    const float* x   = (const float*)d_in[0];
    const int*   ei  = (const int*)d_in[1];
    const float* W1  = (const float*)d_in[2];
    const float* as1 = (const float*)d_in[3];
    const float* ad1 = (const float*)d_in[4];
    const float* b1  = (const float*)d_in[5];
    const float* W2  = (const float*)d_in[6];
    const float* as2 = (const float*)d_in[7];
    const float* ad2 = (const float*)d_in[8];
    const float* b2  = (const float*)d_in[9];
    float* out = (float*)d_out;

    const int N = in_sizes[0] / F_IN;
    const int E = in_sizes[1] / 2;
    const int* esrc = ei;
    const int* edst = ei + E;

    char* ws = (char*)d_ws;
    size_t o = 0;
    auto alloc = [&](size_t bytes) -> void* {
        o = (o + 255) & ~(size_t)255;
        void* p = ws + o;
        o += bytes;
        return p;
    };
    float* h1    = (float*)alloc((size_t)N * HC1 * 4);
    float* asrc1 = (float*)alloc((size_t)N * 4 * 4);
    float* adst1 = (float*)alloc((size_t)N * 4 * 4);
    float* h2    = (float*)alloc((size_t)N * 2 * 4);
    float* asrc2 = (float*)alloc((size_t)N * 4);
    float* adst2 = (float*)alloc((size_t)N * 4);
    int*   deg   = (int*)alloc((size_t)N * 4);
    int*   off   = (int*)alloc((size_t)(N + 1) * 4);
    int*   cur   = (int*)alloc((size_t)N * 4);
    int*   srcs  = (int*)alloc((size_t)(E + N) * 4);
    int*   bsums = (int*)alloc(512);

    // GEMM1 + attention scalars
    dim3 gg((N + 63) / 64, HC1 / 64);
    k_gemm1<<<gg, 256, 0, stream>>>(x, W1, h1, N);
    k_att1<<<(N * 4 + 255) / 256, 256, 0, stream>>>(h1, as1, ad1, asrc1, adst1, N);

    // CSR build (counting sort by dst, self-loops included)
    k_deg_init<<<(N + 255) / 256, 256, 0, stream>>>(deg, N);
    k_count<<<(E + 255) / 256, 256, 0, stream>>>(edst, deg, E);
    int B = (N + 1023) / 1024;
    k_scanA<<<B, 256, 0, stream>>>(deg, off, bsums, N);
    k_scanB<<<1, 128, 0, stream>>>(bsums, B);
    k_scanC<<<(N + 255) / 256, 256, 0, stream>>>(off, bsums, N);
    k_copy_cursor<<<(N + 255) / 256, 256, 0, stream>>>(off, cur, N);
    k_scatter<<<(E + N + 255) / 256, 256, 0, stream>>>(esrc, edst, cur, srcs, E, N);

    // layer-1 aggregation (+ fused relu, W2 projection, att2 scalars)
    k_agg1<<<N, 256, 0, stream>>>(h1, asrc1, adst1, off, srcs, b1, W2, as2, ad2,
                                  h2, asrc2, adst2);

    // layer-2 aggregation + log_softmax
    k_l2<<<(N + 255) / 256, 256, 0, stream>>>(h2, asrc2, adst2, off, srcs, b2, out, N);
}

// Round 4
// 473.205 us; speedup vs baseline: 1.2207x; 1.2207x over previous
//
#include <hip/hip_runtime.h>
#include <cstdint>
#include <cstddef>

#define F_IN 165
#define KP   192      // K padded to multiple of 32
#define HC1  256      // heads*out_ch of layer 1
#define NEG_SLOPE 0.2f

typedef __attribute__((ext_vector_type(8))) short short8;
typedef __attribute__((ext_vector_type(8))) unsigned short ushort8;
typedef __attribute__((ext_vector_type(4))) float f32x4;

static __device__ __forceinline__ float lrelu(float z) {
    return z > 0.f ? z : NEG_SLOPE * z;
}
static __device__ __forceinline__ unsigned short f2b(float v) {
    union { float f; unsigned u; } x; x.f = v;
    unsigned r = (x.u + 0x7FFFu + ((x.u >> 16) & 1u)) >> 16;   // RNE
    return (unsigned short)r;
}
static __device__ __forceinline__ float b2f(unsigned short u) {
    return __uint_as_float(((unsigned)u) << 16);
}
// XOR swizzle: spreads same-column reads across 16B slots (G4 fix).
// Row stride 384 B is a multiple of 128, so XOR of bits 4..6 stays in-row: bijective.
static __device__ __forceinline__ int swzb(int r, int kbyte) {
    return (r * (KP * 2) + kbyte) ^ ((r & 7) << 4);
}

// -------------------- W1 -> bf16 transposed [256][192] --------------------
__global__ void k_prepw(const float* __restrict__ W1, unsigned short* __restrict__ w1t) {
    int i = blockIdx.x * 256 + threadIdx.x;
    if (i >= HC1 * KP) return;
    int n = i / KP, k = i - n * KP;
    float v = (k < F_IN) ? W1[(size_t)k * HC1 + n] : 0.f;
    w1t[i] = f2b(v);
}

// -------------------- GEMM1 (bf16 MFMA): h1b[N,256] = x[N,165] @ W1 --------------------
// grid (4, M/64): blockIdx.x = column block (head), fast-varying for x L2 reuse
__global__ __launch_bounds__(256) void k_gemm1b(const float* __restrict__ x,
        const unsigned short* __restrict__ w1t, unsigned short* __restrict__ h1b, int M)
{
    __shared__ unsigned short xs[64 * KP];
    __shared__ unsigned short ws[64 * KP];
    const int t = threadIdx.x;
    const int col0 = blockIdx.x * 64;
    const int row0 = blockIdx.y * 64;
    // stage X tile (fp32 -> bf16, swizzled)
    for (int e = t; e < 64 * KP; e += 256) {
        int r = e / KP, k = e - r * KP;
        int gr = row0 + r;
        float v = 0.f;
        if (gr < M && k < F_IN) v = x[(size_t)gr * F_IN + k];
        *(unsigned short*)((char*)xs + swzb(r, 2 * k)) = f2b(v);
    }
    // stage W^T tile (bf16, TRUE 16B chunks, swizzled)
    for (int c = t; c < 64 * (KP / 8); c += 256) {
        int nn = c / (KP / 8), k8 = c - nn * (KP / 8);
        ushort8 v = *reinterpret_cast<const ushort8*>(w1t + (size_t)(col0 + nn) * KP + k8 * 8);
        *reinterpret_cast<ushort8*>((char*)ws + swzb(nn, k8 * 16)) = v;
    }
    __syncthreads();
    const int l = t & 63, wid = t >> 6;
    const int wr = wid >> 1, wc = wid & 1;
    f32x4 acc[2][2] = {};
    #pragma unroll
    for (int ks = 0; ks < KP / 32; ++ks) {
        const int kb = ks * 32 + (l >> 4) * 8;
        short8 a[2], b[2];
        #pragma unroll
        for (int f = 0; f < 2; ++f) {
            int ar = wr * 32 + f * 16 + (l & 15);
            a[f] = *reinterpret_cast<const short8*>((const char*)xs + swzb(ar, 2 * kb));
            int bc = wc * 32 + f * 16 + (l & 15);
            b[f] = *reinterpret_cast<const short8*>((const char*)ws + swzb(bc, 2 * kb));
        }
        #pragma unroll
        for (int fi = 0; fi < 2; ++fi)
            #pragma unroll
            for (int fj = 0; fj < 2; ++fj)
                acc[fi][fj] = __builtin_amdgcn_mfma_f32_16x16x32_bf16(a[fi], b[fj], acc[fi][fj], 0, 0, 0);
    }
    #pragma unroll
    for (int fi = 0; fi < 2; ++fi) {
        #pragma unroll
        for (int q = 0; q < 4; ++q) {
            int r = row0 + wr * 32 + fi * 16 + (l >> 4) * 4 + q;
            if (r < M) {
                #pragma unroll
                for (int fj = 0; fj < 2; ++fj) {
                    int cidx = col0 + wc * 32 + fj * 16 + (l & 15);
                    h1b[(size_t)r * HC1 + cidx] = f2b(acc[fi][fj][q]);
                }
            }
        }
    }
}

// -------------------- attention scalars layer 1 --------------------
__global__ void k_att1(const unsigned short* __restrict__ h1b,
                       const float* __restrict__ as1, const float* __restrict__ ad1,
                       float* __restrict__ asrc, float* __restrict__ adst, int N)
{
    int idx = blockIdx.x * blockDim.x + threadIdx.x;
    if (idx >= N * 4) return;
    int n = idx >> 2, h = idx & 3;
    const ushort4* hp = reinterpret_cast<const ushort4*>(h1b + (size_t)n * HC1 + h * 64);
    const float4* sp = reinterpret_cast<const float4*>(as1 + h * 64);
    const float4* dp = reinterpret_cast<const float4*>(ad1 + h * 64);
    float ss = 0.f, dd = 0.f;
    #pragma unroll
    for (int k = 0; k < 16; ++k) {
        ushort4 v = hp[k]; float4 a = sp[k], b = dp[k];
        float v0 = b2f(v.x), v1 = b2f(v.y), v2 = b2f(v.z), v3 = b2f(v.w);
        ss += v0 * a.x + v1 * a.y + v2 * a.z + v3 * a.w;
        dd += v0 * b.x + v1 * b.y + v2 * b.z + v3 * b.w;
    }
    asrc[idx] = ss;
    adst[idx] = dd;
}

// -------------------- CSR build --------------------
__global__ void k_deg_init(int* __restrict__ deg, int N) {
    int i = blockIdx.x * blockDim.x + threadIdx.x;
    if (i < N) deg[i] = 1;   // self loop
}
__global__ void k_count(const int* __restrict__ dst, int* __restrict__ deg, int E) {
    int e = blockIdx.x * blockDim.x + threadIdx.x;
    if (e < E) atomicAdd(&deg[dst[e]], 1);
}
__global__ __launch_bounds__(256) void k_scanA(const int* __restrict__ deg,
                                               int* __restrict__ off,
                                               int* __restrict__ bsums, int n)
{
    __shared__ int s[256];
    const int b = blockIdx.x, t = threadIdx.x;
    const int base = b * 1024 + t * 4;
    int v[4]; int sum = 0;
    #pragma unroll
    for (int j = 0; j < 4; ++j) { v[j] = (base + j < n) ? deg[base + j] : 0; sum += v[j]; }
    s[t] = sum;
    __syncthreads();
    for (int d = 1; d < 256; d <<= 1) {
        int xv = (t >= d) ? s[t - d] : 0;
        __syncthreads();
        s[t] += xv;
        __syncthreads();
    }
    int run = s[t] - sum;
    #pragma unroll
    for (int j = 0; j < 4; ++j) { run += v[j]; if (base + j < n) off[base + j + 1] = run; }
    if (t == 255) bsums[b] = s[255];
    if (b == 0 && t == 0) off[0] = 0;
}
__global__ __launch_bounds__(128) void k_scanB(int* __restrict__ bsums, int B) {
    __shared__ int s[128];
    const int t = threadIdx.x;
    int v = (t < B) ? bsums[t] : 0;
    s[t] = v;
    __syncthreads();
    for (int d = 1; d < 128; d <<= 1) {
        int xv = (t >= d) ? s[t - d] : 0;
        __syncthreads();
        s[t] += xv;
        __syncthreads();
    }
    if (t < B) bsums[t] = s[t] - v;
}
__global__ void k_scanC(int* __restrict__ off, const int* __restrict__ bsums, int n) {
    int i = blockIdx.x * blockDim.x + threadIdx.x;
    if (i < n) off[i + 1] += bsums[i >> 10];
}
__global__ void k_copy_cursor(const int* __restrict__ off, int* __restrict__ cur, int n) {
    int i = blockIdx.x * blockDim.x + threadIdx.x;
    if (i < n) cur[i] = off[i];
}
__global__ void k_scatter(const int* __restrict__ src, const int* __restrict__ dst,
                          int* __restrict__ cur, int* __restrict__ srcs, int E, int N)
{
    int i = blockIdx.x * blockDim.x + threadIdx.x;
    if (i >= E + N) return;
    int s, d;
    if (i < E) { s = src[i]; d = dst[i]; }
    else       { s = i - E; d = i - E; }
    int p = atomicAdd(&cur[d], 1);
    srcs[p] = s;
}

// -------------------- normalized attention weights per CSR slot --------------------
__global__ void k_alpha(const float* __restrict__ asrc1, const float* __restrict__ adst1,
                        const int* __restrict__ off, const int* __restrict__ srcs,
                        float* __restrict__ alpha, int N)
{
    int idx = blockIdx.x * blockDim.x + threadIdx.x;
    if (idx >= N * 4) return;
    int n = idx >> 2, h = idx & 3;
    float adh = adst1[idx];
    int p0 = off[n], p1 = off[n + 1];
    float m = -INFINITY;
    for (int p = p0; p < p1; ++p)
        m = fmaxf(m, lrelu(asrc1[srcs[p] * 4 + h] + adh));
    float ssum = 0.f;
    for (int p = p0; p < p1; ++p) {
        float e = __expf(lrelu(asrc1[srcs[p] * 4 + h] + adh) - m);
        alpha[p * 4 + h] = e;
        ssum += e;
    }
    float inv = 1.f / ssum;
    for (int p = p0; p < p1; ++p) alpha[p * 4 + h] *= inv;
}

// -------------------- layer-1 aggregation (pure gather-fma) + fused layer-2 proj ----
// 256-thread block = 4 independent waves, one wave per dst node; lane owns 4 channels
__global__ __launch_bounds__(256) void k_agg1b(const unsigned short* __restrict__ h1b,
        const float* __restrict__ alpha, const int* __restrict__ off,
        const int* __restrict__ srcs, const float* __restrict__ b1,
        const float* __restrict__ W2, const float* __restrict__ as2,
        const float* __restrict__ ad2, float* __restrict__ h2,
        float* __restrict__ asrc2, float* __restrict__ adst2, int N)
{
    const int lane = threadIdx.x & 63;
    const int n = blockIdx.x * 4 + (threadIdx.x >> 6);
    if (n >= N) return;
    const int head = lane >> 4;
    const int p0 = off[n], p1 = off[n + 1];
    float a0 = 0.f, a1 = 0.f, a2 = 0.f, a3 = 0.f;
    for (int p = p0; p < p1; ++p) {
        const int s = srcs[p];
        const float al = alpha[p * 4 + head];
        ushort4 hv = *reinterpret_cast<const ushort4*>(h1b + (size_t)s * HC1 + lane * 4);
        a0 += al * b2f(hv.x); a1 += al * b2f(hv.y);
        a2 += al * b2f(hv.z); a3 += al * b2f(hv.w);
    }
    const float4 bb = *reinterpret_cast<const float4*>(b1 + lane * 4);
    a0 = fmaxf(a0 + bb.x, 0.f); a1 = fmaxf(a1 + bb.y, 0.f);
    a2 = fmaxf(a2 + bb.z, 0.f); a3 = fmaxf(a3 + bb.w, 0.f);
    // layer-2 projection: out-row (256) @ W2 (256x2)
    const float4 wA = *reinterpret_cast<const float4*>(W2 + lane * 8);
    const float4 wB = *reinterpret_cast<const float4*>(W2 + lane * 8 + 4);
    float q0 = a0 * wA.x + a1 * wA.z + a2 * wB.x + a3 * wB.z;
    float q1 = a0 * wA.y + a1 * wA.w + a2 * wB.y + a3 * wB.w;
    #pragma unroll
    for (int d = 1; d < 64; d <<= 1) {
        q0 += __shfl_xor(q0, d, 64);
        q1 += __shfl_xor(q1, d, 64);
    }
    if (lane == 0) {
        h2[n * 2 + 0] = q0; h2[n * 2 + 1] = q1;
        asrc2[n] = q0 * as2[0] + q1 * as2[1];
        adst2[n] = q0 * ad2[0] + q1 * ad2[1];
    }
}

// -------------------- layer-2 aggregation + log_softmax --------------------
__global__ void k_l2(const float* __restrict__ h2, const float* __restrict__ asrc2,
                     const float* __restrict__ adst2, const int* __restrict__ off,
                     const int* __restrict__ srcs, const float* __restrict__ b2,
                     float* __restrict__ out, int N)
{
    int n = blockIdx.x * blockDim.x + threadIdx.x;
    if (n >= N) return;
    const float adn = adst2[n];
    float m = -INFINITY, ssum = 0.f, a0 = 0.f, a1 = 0.f;
    const int p1 = off[n + 1];
    for (int p = off[n]; p < p1; ++p) {
        int s = srcs[p];
        float l = lrelu(asrc2[s] + adn);
        if (l > m) {
            float sc = __expf(m - l);
            ssum *= sc; a0 *= sc; a1 *= sc; m = l;
        }
        float w = __expf(l - m);
        ssum += w;
        a0 += w * h2[s * 2 + 0];
        a1 += w * h2[s * 2 + 1];
    }
    float o0 = a0 / ssum + b2[0];
    float o1 = a1 / ssum + b2[1];
    float mm = fmaxf(o0, o1);
    float lse = mm + __logf(__expf(o0 - mm) + __expf(o1 - mm));
    out[n * 2 + 0] = o0 - lse;
    out[n * 2 + 1] = o1 - lse;
}

extern "C" void kernel_launch(void* const* d_in, const int* in_sizes, int n_in,
                              void* d_out, int out_size, void* d_ws, size_t ws_size,
                              hipStream_t stream)
{
    const float* x   = (const float*)d_in[0];
    const int*   ei  = (const int*)d_in[1];
    const float* W1  = (const float*)d_in[2];
    const float* as1 = (const float*)d_in[3];
    const float* ad1 = (const float*)d_in[4];
    const float* b1  = (const float*)d_in[5];
    const float* W2  = (const float*)d_in[6];
    const float* as2 = (const float*)d_in[7];
    const float* ad2 = (const float*)d_in[8];
    const float* b2  = (const float*)d_in[9];
    float* out = (float*)d_out;

    const int N = in_sizes[0] / F_IN;
    const int E = in_sizes[1] / 2;
    const int* esrc = ei;
    const int* edst = ei + E;

    char* ws = (char*)d_ws;
    size_t o = 0;
    auto alloc = [&](size_t bytes) -> void* {
        o = (o + 255) & ~(size_t)255;
        void* p = ws + o;
        o += bytes;
        return p;
    };
    unsigned short* w1t  = (unsigned short*)alloc((size_t)HC1 * KP * 2);
    unsigned short* h1b  = (unsigned short*)alloc((size_t)N * HC1 * 2);
    float* asrc1 = (float*)alloc((size_t)N * 4 * 4);
    float* adst1 = (float*)alloc((size_t)N * 4 * 4);
    float* alpha = (float*)alloc((size_t)(E + N) * 4 * 4);
    float* h2    = (float*)alloc((size_t)N * 2 * 4);
    float* asrc2 = (float*)alloc((size_t)N * 4);
    float* adst2 = (float*)alloc((size_t)N * 4);
    int*   deg   = (int*)alloc((size_t)N * 4);
    int*   off   = (int*)alloc((size_t)(N + 1) * 4);
    int*   cur   = (int*)alloc((size_t)N * 4);
    int*   srcs  = (int*)alloc((size_t)(E + N) * 4);
    int*   bsums = (int*)alloc(512);

    // projections
    k_prepw<<<(HC1 * KP + 255) / 256, 256, 0, stream>>>(W1, w1t);
    dim3 gg(4, (N + 63) / 64);
    k_gemm1b<<<gg, 256, 0, stream>>>(x, w1t, h1b, N);
    k_att1<<<(N * 4 + 255) / 256, 256, 0, stream>>>(h1b, as1, ad1, asrc1, adst1, N);

    // CSR build
    k_deg_init<<<(N + 255) / 256, 256, 0, stream>>>(deg, N);
    k_count<<<(E + 255) / 256, 256, 0, stream>>>(edst, deg, E);
    int B = (N + 1023) / 1024;
    k_scanA<<<B, 256, 0, stream>>>(deg, off, bsums, N);
    k_scanB<<<1, 128, 0, stream>>>(bsums, B);
    k_scanC<<<(N + 255) / 256, 256, 0, stream>>>(off, bsums, N);
    k_copy_cursor<<<(N + 255) / 256, 256, 0, stream>>>(off, cur, N);
    k_scatter<<<(E + N + 255) / 256, 256, 0, stream>>>(esrc, edst, cur, srcs, E, N);

    // attention weights, aggregation, layer 2
    k_alpha<<<(N * 4 + 255) / 256, 256, 0, stream>>>(asrc1, adst1, off, srcs, alpha, N);
    k_agg1b<<<(N + 3) / 4, 256, 0, stream>>>(h1b, alpha, off, srcs, b1, W2, as2, ad2,
                                             h2, asrc2, adst2, N);
    k_l2<<<(N + 255) / 256, 256, 0, stream>>>(h2, asrc2, adst2, off, srcs, b2, out, N);
}

// Round 5
// 348.249 us; speedup vs baseline: 1.6587x; 1.3588x over previous
//
#include <hip/hip_runtime.h>
#include <cstdint>
#include <cstddef>

#define F_IN 165
#define KP   192      // K padded to multiple of 32
#define HC1  256      // heads*out_ch of layer 1
#define NEG_SLOPE 0.2f

typedef __attribute__((ext_vector_type(8))) short short8;
typedef __attribute__((ext_vector_type(8))) unsigned short ushort8;
typedef __attribute__((ext_vector_type(4))) float f32x4;

static __device__ __forceinline__ float lrelu(float z) {
    return z > 0.f ? z : NEG_SLOPE * z;
}
static __device__ __forceinline__ unsigned short f2b(float v) {
    union { float f; unsigned u; } x; x.f = v;
    unsigned r = (x.u + 0x7FFFu + ((x.u >> 16) & 1u)) >> 16;   // RNE
    return (unsigned short)r;
}
static __device__ __forceinline__ float b2f(unsigned short u) {
    return __uint_as_float(((unsigned)u) << 16);
}
// XOR swizzle within a row (row = 384 B): byte_in_row' = byte_in_row ^ ((r&7)<<4).
// Bits 4-6 of the in-row byte offset are toggled -> stays in-row, bijective,
// spreads the 8 rows of a quarter-wave ds_read_b128 across 8 bank groups.
static __device__ __forceinline__ int swzb(int r, int kbyte) {
    return r * (KP * 2) + (kbyte ^ ((r & 7) << 4));
}

// -------------------- x[N,165] fp32 -> xb[N,192] bf16, PRE-SWIZZLED --------------------
__global__ void k_prepx(const float* __restrict__ x, unsigned short* __restrict__ xb, int N) {
    int i = blockIdx.x * 256 + threadIdx.x;      // quad index: (row, q) q<48
    if (i >= N * 48) return;
    int r = i / 48, q = i - r * 48;
    int k = q * 4;
    ushort4 o;
    o.x = f2b((k + 0 < F_IN) ? x[(size_t)r * F_IN + k + 0] : 0.f);
    o.y = f2b((k + 1 < F_IN) ? x[(size_t)r * F_IN + k + 1] : 0.f);
    o.z = f2b((k + 2 < F_IN) ? x[(size_t)r * F_IN + k + 2] : 0.f);
    o.w = f2b((k + 3 < F_IN) ? x[(size_t)r * F_IN + k + 3] : 0.f);
    int byte = (8 * q) ^ ((r & 7) << 4);
    *reinterpret_cast<ushort4*>((char*)xb + (size_t)r * (KP * 2) + byte) = o;
}

// -------------------- W1 -> w1t[256,192] bf16 transposed, PRE-SWIZZLED --------------------
__global__ void k_prepw(const float* __restrict__ W1, unsigned short* __restrict__ w1t) {
    int i = blockIdx.x * 256 + threadIdx.x;      // (ncol, q)
    if (i >= HC1 * 48) return;
    int nc = i / 48, q = i - nc * 48;
    int k = q * 4;
    ushort4 o;
    o.x = f2b((k + 0 < F_IN) ? W1[(size_t)(k + 0) * HC1 + nc] : 0.f);
    o.y = f2b((k + 1 < F_IN) ? W1[(size_t)(k + 1) * HC1 + nc] : 0.f);
    o.z = f2b((k + 2 < F_IN) ? W1[(size_t)(k + 2) * HC1 + nc] : 0.f);
    o.w = f2b((k + 3 < F_IN) ? W1[(size_t)(k + 3) * HC1 + nc] : 0.f);
    int byte = (8 * q) ^ ((nc & 7) << 4);
    *reinterpret_cast<ushort4*>((char*)w1t + (size_t)nc * (KP * 2) + byte) = o;
}

// -------------------- GEMM1 (bf16 MFMA): h1b[N,256] = xb @ w1t^T --------------------
// grid (4, Nr/64): blockIdx.x = column block (head), fast-varying for x L2 reuse.
// Tiles are linear copies of pre-swizzled global panels: staging = pure 16B moves.
__global__ __launch_bounds__(256) void k_gemm1b(const unsigned short* __restrict__ xb,
        const unsigned short* __restrict__ w1t, unsigned short* __restrict__ h1b, int M)
{
    __shared__ unsigned short xs[64 * KP];
    __shared__ unsigned short wt[64 * KP];
    const int t = threadIdx.x;
    const int col0 = blockIdx.x * 64;
    const int row0 = blockIdx.y * 64;
    const char* gx = (const char*)xb  + (size_t)row0 * (KP * 2);
    const char* gw = (const char*)w1t + (size_t)col0 * (KP * 2);
    #pragma unroll
    for (int i = 0; i < 6; ++i) {
        int off = i * 4096 + t * 16;
        *reinterpret_cast<ushort8*>((char*)xs + off) =
            *reinterpret_cast<const ushort8*>(gx + off);
        *reinterpret_cast<ushort8*>((char*)wt + off) =
            *reinterpret_cast<const ushort8*>(gw + off);
    }
    __syncthreads();
    const int l = t & 63, wid = t >> 6;
    const int wr = wid >> 1, wc = wid & 1;
    f32x4 acc[2][2] = {};
    #pragma unroll
    for (int ks = 0; ks < KP / 32; ++ks) {
        const int kb = ks * 32 + (l >> 4) * 8;
        short8 a[2], b[2];
        #pragma unroll
        for (int f = 0; f < 2; ++f) {
            int ar = wr * 32 + f * 16 + (l & 15);
            a[f] = *reinterpret_cast<const short8*>((const char*)xs + swzb(ar, 2 * kb));
            int bc = wc * 32 + f * 16 + (l & 15);
            b[f] = *reinterpret_cast<const short8*>((const char*)wt + swzb(bc, 2 * kb));
        }
        #pragma unroll
        for (int fi = 0; fi < 2; ++fi)
            #pragma unroll
            for (int fj = 0; fj < 2; ++fj)
                acc[fi][fj] = __builtin_amdgcn_mfma_f32_16x16x32_bf16(a[fi], b[fj], acc[fi][fj], 0, 0, 0);
    }
    #pragma unroll
    for (int fi = 0; fi < 2; ++fi) {
        #pragma unroll
        for (int q = 0; q < 4; ++q) {
            int r = row0 + wr * 32 + fi * 16 + (l >> 4) * 4 + q;
            if (r < M) {
                #pragma unroll
                for (int fj = 0; fj < 2; ++fj) {
                    int cidx = col0 + wc * 32 + fj * 16 + (l & 15);
                    h1b[(size_t)r * HC1 + cidx] = f2b(acc[fi][fj][q]);
                }
            }
        }
    }
}

// -------------------- attention scalars layer 1 --------------------
__global__ void k_att1(const unsigned short* __restrict__ h1b,
                       const float* __restrict__ as1, const float* __restrict__ ad1,
                       float* __restrict__ asrc, float* __restrict__ adst, int N)
{
    int idx = blockIdx.x * blockDim.x + threadIdx.x;
    if (idx >= N * 4) return;
    int n = idx >> 2, h = idx & 3;
    const ushort4* hp = reinterpret_cast<const ushort4*>(h1b + (size_t)n * HC1 + h * 64);
    const float4* sp = reinterpret_cast<const float4*>(as1 + h * 64);
    const float4* dp = reinterpret_cast<const float4*>(ad1 + h * 64);
    float ss = 0.f, dd = 0.f;
    #pragma unroll
    for (int k = 0; k < 16; ++k) {
        ushort4 v = hp[k]; float4 a = sp[k], b = dp[k];
        float v0 = b2f(v.x), v1 = b2f(v.y), v2 = b2f(v.z), v3 = b2f(v.w);
        ss += v0 * a.x + v1 * a.y + v2 * a.z + v3 * a.w;
        dd += v0 * b.x + v1 * b.y + v2 * b.z + v3 * b.w;
    }
    asrc[idx] = ss;
    adst[idx] = dd;
}

// -------------------- CSR build --------------------
__global__ void k_deg_init(int* __restrict__ deg, int N) {
    int i = blockIdx.x * blockDim.x + threadIdx.x;
    if (i < N) deg[i] = 1;   // self loop
}
__global__ void k_count(const int* __restrict__ dst, int* __restrict__ deg, int E) {
    int e = blockIdx.x * blockDim.x + threadIdx.x;
    if (e < E) atomicAdd(&deg[dst[e]], 1);
}
__global__ __launch_bounds__(256) void k_scanA(const int* __restrict__ deg,
                                               int* __restrict__ off,
                                               int* __restrict__ bsums, int n)
{
    __shared__ int s[256];
    const int b = blockIdx.x, t = threadIdx.x;
    const int base = b * 1024 + t * 4;
    int v[4]; int sum = 0;
    #pragma unroll
    for (int j = 0; j < 4; ++j) { v[j] = (base + j < n) ? deg[base + j] : 0; sum += v[j]; }
    s[t] = sum;
    __syncthreads();
    for (int d = 1; d < 256; d <<= 1) {
        int xv = (t >= d) ? s[t - d] : 0;
        __syncthreads();
        s[t] += xv;
        __syncthreads();
    }
    int run = s[t] - sum;
    #pragma unroll
    for (int j = 0; j < 4; ++j) { run += v[j]; if (base + j < n) off[base + j + 1] = run; }
    if (t == 255) bsums[b] = s[255];
    if (b == 0 && t == 0) off[0] = 0;
}
__global__ __launch_bounds__(128) void k_scanB(int* __restrict__ bsums, int B) {
    __shared__ int s[128];
    const int t = threadIdx.x;
    int v = (t < B) ? bsums[t] : 0;
    s[t] = v;
    __syncthreads();
    for (int d = 1; d < 128; d <<= 1) {
        int xv = (t >= d) ? s[t - d] : 0;
        __syncthreads();
        s[t] += xv;
        __syncthreads();
    }
    if (t < B) bsums[t] = s[t] - v;
}
__global__ void k_scanC(int* __restrict__ off, const int* __restrict__ bsums, int n) {
    int i = blockIdx.x * blockDim.x + threadIdx.x;
    if (i < n) off[i + 1] += bsums[i >> 10];
}
__global__ void k_copy_cursor(const int* __restrict__ off, int* __restrict__ cur, int n) {
    int i = blockIdx.x * blockDim.x + threadIdx.x;
    if (i < n) cur[i] = off[i];
}
__global__ void k_scatter(const int* __restrict__ src, const int* __restrict__ dst,
                          int* __restrict__ cur, int* __restrict__ srcs, int E, int N)
{
    int i = blockIdx.x * blockDim.x + threadIdx.x;
    if (i >= E + N) return;
    int s, d;
    if (i < E) { s = src[i]; d = dst[i]; }
    else       { s = i - E; d = i - E; }
    int p = atomicAdd(&cur[d], 1);
    srcs[p] = s;
}

// -------------------- normalized attention weights per CSR slot --------------------
__global__ void k_alpha(const float* __restrict__ asrc1, const float* __restrict__ adst1,
                        const int* __restrict__ off, const int* __restrict__ srcs,
                        float* __restrict__ alpha, int N)
{
    int idx = blockIdx.x * blockDim.x + threadIdx.x;
    if (idx >= N * 4) return;
    int n = idx >> 2, h = idx & 3;
    float adh = adst1[idx];
    int p0 = off[n], p1 = off[n + 1];
    float m = -INFINITY;
    for (int p = p0; p < p1; ++p)
        m = fmaxf(m, lrelu(asrc1[srcs[p] * 4 + h] + adh));
    float ssum = 0.f;
    for (int p = p0; p < p1; ++p) {
        float e = __expf(lrelu(asrc1[srcs[p] * 4 + h] + adh) - m);
        alpha[p * 4 + h] = e;
        ssum += e;
    }
    float inv = 1.f / ssum;
    for (int p = p0; p < p1; ++p) alpha[p * 4 + h] *= inv;
}

// -------------------- layer-1 aggregation (pure gather-fma) + fused layer-2 proj ----
// 256-thread block = 4 independent waves, one wave per dst node; lane owns 4 channels
__global__ __launch_bounds__(256) void k_agg1b(const unsigned short* __restrict__ h1b,
        const float* __restrict__ alpha, const int* __restrict__ off,
        const int* __restrict__ srcs, const float* __restrict__ b1,
        const float* __restrict__ W2, const float* __restrict__ as2,
        const float* __restrict__ ad2, float* __restrict__ h2,
        float* __restrict__ asrc2, float* __restrict__ adst2, int N)
{
    const int lane = threadIdx.x & 63;
    const int n = blockIdx.x * 4 + (threadIdx.x >> 6);
    if (n >= N) return;
    const int head = lane >> 4;
    const int p0 = off[n], p1 = off[n + 1];
    float a0 = 0.f, a1 = 0.f, a2 = 0.f, a3 = 0.f;
    for (int p = p0; p < p1; ++p) {
        const int s = srcs[p];
        const float al = alpha[p * 4 + head];
        ushort4 hv = *reinterpret_cast<const ushort4*>(h1b + (size_t)s * HC1 + lane * 4);
        a0 += al * b2f(hv.x); a1 += al * b2f(hv.y);
        a2 += al * b2f(hv.z); a3 += al * b2f(hv.w);
    }
    const float4 bb = *reinterpret_cast<const float4*>(b1 + lane * 4);
    a0 = fmaxf(a0 + bb.x, 0.f); a1 = fmaxf(a1 + bb.y, 0.f);
    a2 = fmaxf(a2 + bb.z, 0.f); a3 = fmaxf(a3 + bb.w, 0.f);
    // layer-2 projection: out-row (256) @ W2 (256x2)
    const float4 wA = *reinterpret_cast<const float4*>(W2 + lane * 8);
    const float4 wB = *reinterpret_cast<const float4*>(W2 + lane * 8 + 4);
    float q0 = a0 * wA.x + a1 * wA.z + a2 * wB.x + a3 * wB.z;
    float q1 = a0 * wA.y + a1 * wA.w + a2 * wB.y + a3 * wB.w;
    #pragma unroll
    for (int d = 1; d < 64; d <<= 1) {
        q0 += __shfl_xor(q0, d, 64);
        q1 += __shfl_xor(q1, d, 64);
    }
    if (lane == 0) {
        h2[n * 2 + 0] = q0; h2[n * 2 + 1] = q1;
        asrc2[n] = q0 * as2[0] + q1 * as2[1];
        adst2[n] = q0 * ad2[0] + q1 * ad2[1];
    }
}

// -------------------- layer-2 aggregation + log_softmax --------------------
__global__ void k_l2(const float* __restrict__ h2, const float* __restrict__ asrc2,
                     const float* __restrict__ adst2, const int* __restrict__ off,
                     const int* __restrict__ srcs, const float* __restrict__ b2,
                     float* __restrict__ out, int N)
{
    int n = blockIdx.x * blockDim.x + threadIdx.x;
    if (n >= N) return;
    const float adn = adst2[n];
    float m = -INFINITY, ssum = 0.f, a0 = 0.f, a1 = 0.f;
    const int p1 = off[n + 1];
    for (int p = off[n]; p < p1; ++p) {
        int s = srcs[p];
        float l = lrelu(asrc2[s] + adn);
        if (l > m) {
            float sc = __expf(m - l);
            ssum *= sc; a0 *= sc; a1 *= sc; m = l;
        }
        float w = __expf(l - m);
        ssum += w;
        a0 += w * h2[s * 2 + 0];
        a1 += w * h2[s * 2 + 1];
    }
    float o0 = a0 / ssum + b2[0];
    float o1 = a1 / ssum + b2[1];
    float mm = fmaxf(o0, o1);
    float lse = mm + __logf(__expf(o0 - mm) + __expf(o1 - mm));
    out[n * 2 + 0] = o0 - lse;
    out[n * 2 + 1] = o1 - lse;
}

extern "C" void kernel_launch(void* const* d_in, const int* in_sizes, int n_in,
                              void* d_out, int out_size, void* d_ws, size_t ws_size,
                              hipStream_t stream)
{
    const float* x   = (const float*)d_in[0];
    const int*   ei  = (const int*)d_in[1];
    const float* W1  = (const float*)d_in[2];
    const float* as1 = (const float*)d_in[3];
    const float* ad1 = (const float*)d_in[4];
    const float* b1  = (const float*)d_in[5];
    const float* W2  = (const float*)d_in[6];
    const float* as2 = (const float*)d_in[7];
    const float* ad2 = (const float*)d_in[8];
    const float* b2  = (const float*)d_in[9];
    float* out = (float*)d_out;

    const int N = in_sizes[0] / F_IN;
    const int E = in_sizes[1] / 2;
    const int Nr = (N + 63) & ~63;          // rows rounded to tile
    const int* esrc = ei;
    const int* edst = ei + E;

    char* ws = (char*)d_ws;
    size_t o = 0;
    auto alloc = [&](size_t bytes) -> void* {
        o = (o + 255) & ~(size_t)255;
        void* p = ws + o;
        o += bytes;
        return p;
    };
    unsigned short* xb   = (unsigned short*)alloc((size_t)Nr * KP * 2);
    unsigned short* w1t  = (unsigned short*)alloc((size_t)HC1 * KP * 2);
    unsigned short* h1b  = (unsigned short*)alloc((size_t)N * HC1 * 2);
    float* asrc1 = (float*)alloc((size_t)N * 4 * 4);
    float* adst1 = (float*)alloc((size_t)N * 4 * 4);
    float* alpha = (float*)alloc((size_t)(E + N) * 4 * 4);
    float* h2    = (float*)alloc((size_t)N * 2 * 4);
    float* asrc2 = (float*)alloc((size_t)N * 4);
    float* adst2 = (float*)alloc((size_t)N * 4);
    int*   deg   = (int*)alloc((size_t)N * 4);
    int*   off   = (int*)alloc((size_t)(N + 1) * 4);
    int*   cur   = (int*)alloc((size_t)N * 4);
    int*   srcs  = (int*)alloc((size_t)(E + N) * 4);
    int*   bsums = (int*)alloc(512);

    // projections
    k_prepx<<<(N * 48 + 255) / 256, 256, 0, stream>>>(x, xb, N);
    k_prepw<<<(HC1 * 48 + 255) / 256, 256, 0, stream>>>(W1, w1t);
    dim3 gg(4, Nr / 64);
    k_gemm1b<<<gg, 256, 0, stream>>>(xb, w1t, h1b, N);
    k_att1<<<(N * 4 + 255) / 256, 256, 0, stream>>>(h1b, as1, ad1, asrc1, adst1, N);

    // CSR build
    k_deg_init<<<(N + 255) / 256, 256, 0, stream>>>(deg, N);
    k_count<<<(E + 255) / 256, 256, 0, stream>>>(edst, deg, E);
    int B = (N + 1023) / 1024;
    k_scanA<<<B, 256, 0, stream>>>(deg, off, bsums, N);
    k_scanB<<<1, 128, 0, stream>>>(bsums, B);
    k_scanC<<<(N + 255) / 256, 256, 0, stream>>>(off, bsums, N);
    k_copy_cursor<<<(N + 255) / 256, 256, 0, stream>>>(off, cur, N);
    k_scatter<<<(E + N + 255) / 256, 256, 0, stream>>>(esrc, edst, cur, srcs, E, N);

    // attention weights, aggregation, layer 2
    k_alpha<<<(N * 4 + 255) / 256, 256, 0, stream>>>(asrc1, adst1, off, srcs, alpha, N);
    k_agg1b<<<(N + 3) / 4, 256, 0, stream>>>(h1b, alpha, off, srcs, b1, W2, as2, ad2,
                                             h2, asrc2, adst2, N);
    k_l2<<<(N + 255) / 256, 256, 0, stream>>>(h2, asrc2, adst2, off, srcs, b2, out, N);
}